// Round 7
// baseline (377.900 us; speedup 1.0000x reference)
//
#include <hip/hip_runtime.h>
#include <math.h>

constexpr int Bn = 8, Cn = 512, Sn = 256, Mn = 200, Ln = 100;

// workspace layout (floats) — total ~10.8 MB (R3 proved >=11.6 MB available)
constexpr size_t OFF_V    = 0;                                 // [B][C][S]
constexpr size_t OFF_ZN   = OFF_V    + (size_t)Bn*Cn*Sn;       // [B][M][S] normalized z
constexpr size_t OFF_ZNT  = OFF_ZN   + (size_t)Bn*Mn*Sn;       // [B][S][M] zn transposed
constexpr size_t OFF_P2   = OFF_ZNT  + (size_t)Bn*Sn*Mn;       // [B][C][M] softmax_d(v.phi)
constexpr size_t OFF_ZW   = OFF_P2   + (size_t)Bn*Cn*Mn;       // [B][M]  z.wsum
constexpr size_t OFF_VSUM = OFF_ZW   + (size_t)Bn*Mn;          // [B][C]  sum_s v
constexpr size_t OFF_WSUM = OFF_VSUM + (size_t)Bn*Cn;          // [S]     row-sums of out_w

// ---------- vectorized block reductions (4 waves / 256 threads) ----------
__device__ __forceinline__ float4 blk_max_f4(float4 x, float4* red) {
  #pragma unroll
  for (int o = 32; o; o >>= 1) {
    x.x = fmaxf(x.x, __shfl_xor(x.x, o));
    x.y = fmaxf(x.y, __shfl_xor(x.y, o));
    x.z = fmaxf(x.z, __shfl_xor(x.z, o));
    x.w = fmaxf(x.w, __shfl_xor(x.w, o));
  }
  __syncthreads();
  if ((threadIdx.x & 63) == 0) red[threadIdx.x >> 6] = x;
  __syncthreads();
  float4 r = red[0];
  #pragma unroll
  for (int w = 1; w < 4; ++w) {
    r.x = fmaxf(r.x, red[w].x); r.y = fmaxf(r.y, red[w].y);
    r.z = fmaxf(r.z, red[w].z); r.w = fmaxf(r.w, red[w].w);
  }
  return r;
}
__device__ __forceinline__ float4 blk_sum_f4(float4 x, float4* red) {
  #pragma unroll
  for (int o = 32; o; o >>= 1) {
    x.x += __shfl_xor(x.x, o); x.y += __shfl_xor(x.y, o);
    x.z += __shfl_xor(x.z, o); x.w += __shfl_xor(x.w, o);
  }
  __syncthreads();
  if ((threadIdx.x & 63) == 0) red[threadIdx.x >> 6] = x;
  __syncthreads();
  float4 r = red[0];
  #pragma unroll
  for (int w = 1; w < 4; ++w) {
    r.x += red[w].x; r.y += red[w].y; r.z += red[w].z; r.w += red[w].w;
  }
  return r;
}

// ---------- D1: R2-proven pool: 8x8 block-mean, 1 plane/block + wsum ----------
__global__ void __launch_bounds__(256) k_pool(const float* __restrict__ x,
                                              const float* __restrict__ ow,
                                              float* __restrict__ ws) {
  int t = threadIdx.x;
  if (blockIdx.x == 4096) {                  // wsum[s] = sum_t out_w[s,t]
    const float* row = ow + (size_t)t * Sn;
    float s = 0.f;
    for (int j = 0; j < Sn; j += 4) {
      float4 f = *(const float4*)(row + j);
      s += f.x + f.y + f.z + f.w;
    }
    ws[OFF_WSUM + t] = s;
    return;
  }
  int bc = blockIdx.x;                       // (b,c) plane, 0..4095
  const float* plane = x + (size_t)bc * 16384;
  float part[16];
  #pragma unroll
  for (int i = 0; i < 16; ++i) {
    float4 f = *(const float4*)(plane + i * 1024 + t * 4);
    part[i] = f.x + f.y + f.z + f.w;
  }
  __shared__ float lds[256][17];
  #pragma unroll
  for (int i = 0; i < 16; ++i) lds[t][i] = part[i];
  __syncthreads();
  int i = t >> 4, jj = t & 15;
  float s = 0.f;
  #pragma unroll
  for (int r = 0; r < 8; ++r)
    s += lds[32 * r + 2 * jj][i] + lds[32 * r + 2 * jj + 1][i];
  ws[OFF_V + (size_t)bc * 256 + t] = s * (1.0f / 64.0f);
}

// ---------- D2: blocks 0..399 = psz ; blocks 400..911 = P2 + vsum ----------
struct PszS { float pc[4][256]; float As[4][512]; };
struct P2S  { float vl[8][256]; float t2l[16][104]; };
union MidS { PszS z; P2S p; };

__global__ void __launch_bounds__(256) k_mid(const float* __restrict__ psi,
                                             const float* __restrict__ phi,
                                             float* __restrict__ ws) {
  __shared__ MidS sh;
  __shared__ float4 red4[4];
  int bl = blockIdx.x, t = threadIdx.x;

  if (bl < 400) {
    // ===== psz: t1 = v.psi -> softmax_c -> A(LDS) -> z -> zn/znT/zw
    int b = bl / 50, g = bl % 50, m0 = g * 4;
    const float* v = ws + OFF_V + (size_t)b * Cn * Sn;
    for (int e = t; e < 4 * 256; e += 256) {
      int mm = e >> 8, s = e & 255;
      int m = m0 + mm, k = m / Ln, d = m % Ln;
      sh.z.pc[mm][s] = psi[(size_t)k * Sn * Ln + (size_t)s * Ln + d];
    }
    __syncthreads();
    float acc[2][4];
    #pragma unroll
    for (int mm = 0; mm < 4; ++mm) { acc[0][mm] = 0.f; acc[1][mm] = 0.f; }
    const float* vp0 = v + (size_t)t * Sn;
    const float* vp1 = v + (size_t)(t + 256) * Sn;
    for (int s = 0; s < Sn; s += 4) {
      float4 v0 = *(const float4*)(vp0 + s);
      float4 v1 = *(const float4*)(vp1 + s);
      #pragma unroll
      for (int mm = 0; mm < 4; ++mm) {
        float4 p = *(const float4*)&sh.z.pc[mm][s];
        acc[0][mm] += v0.x * p.x + v0.y * p.y + v0.z * p.z + v0.w * p.w;
        acc[1][mm] += v1.x * p.x + v1.y * p.y + v1.z * p.z + v1.w * p.w;
      }
    }
    float4 a = make_float4(fmaxf(acc[0][0], acc[1][0]), fmaxf(acc[0][1], acc[1][1]),
                           fmaxf(acc[0][2], acc[1][2]), fmaxf(acc[0][3], acc[1][3]));
    float4 mx = blk_max_f4(a, red4);
    float e00 = expf(acc[0][0] - mx.x), e10 = expf(acc[1][0] - mx.x);
    float e01 = expf(acc[0][1] - mx.y), e11 = expf(acc[1][1] - mx.y);
    float e02 = expf(acc[0][2] - mx.z), e12 = expf(acc[1][2] - mx.z);
    float e03 = expf(acc[0][3] - mx.w), e13 = expf(acc[1][3] - mx.w);
    float4 se = blk_sum_f4(make_float4(e00 + e10, e01 + e11, e02 + e12, e03 + e13),
                           red4);
    sh.z.As[0][t] = e00 / se.x; sh.z.As[0][t + 256] = e10 / se.x;
    sh.z.As[1][t] = e01 / se.y; sh.z.As[1][t + 256] = e11 / se.y;
    sh.z.As[2][t] = e02 / se.z; sh.z.As[2][t + 256] = e12 / se.z;
    sh.z.As[3][t] = e03 / se.w; sh.z.As[3][t + 256] = e13 / se.w;
    __syncthreads();
    float zv[4] = {0, 0, 0, 0};
    for (int c = 0; c < Cn; c += 4) {
      float w0 = v[(size_t)(c + 0) * Sn + t];
      float w1 = v[(size_t)(c + 1) * Sn + t];
      float w2 = v[(size_t)(c + 2) * Sn + t];
      float w3 = v[(size_t)(c + 3) * Sn + t];
      #pragma unroll
      for (int mm = 0; mm < 4; ++mm) {
        float4 aa = *(const float4*)&sh.z.As[mm][c];
        zv[mm] += aa.x * w0 + aa.y * w1 + aa.z * w2 + aa.w * w3;
      }
    }
    float wsv = ws[OFF_WSUM + t];
    float4 n2 = blk_sum_f4(make_float4(zv[0]*zv[0], zv[1]*zv[1],
                                       zv[2]*zv[2], zv[3]*zv[3]), red4);
    float4 zw = blk_sum_f4(make_float4(zv[0]*wsv, zv[1]*wsv,
                                       zv[2]*wsv, zv[3]*wsv), red4);
    // normalize in-register (n2/zw are block-wide values) and store zn + znT
    float zn0 = zv[0] * (1.0f / (sqrtf(n2.x) + 1e-6f));
    float zn1 = zv[1] * (1.0f / (sqrtf(n2.y) + 1e-6f));
    float zn2 = zv[2] * (1.0f / (sqrtf(n2.z) + 1e-6f));
    float zn3 = zv[3] * (1.0f / (sqrtf(n2.w) + 1e-6f));
    float* zo = ws + OFF_ZN + ((size_t)b * Mn + m0) * Sn;
    zo[0 * Sn + t] = zn0; zo[1 * Sn + t] = zn1;
    zo[2 * Sn + t] = zn2; zo[3 * Sn + t] = zn3;
    *(float4*)&ws[OFF_ZNT + ((size_t)b * Sn + t) * Mn + m0] =
        make_float4(zn0, zn1, zn2, zn3);
    if (t == 0) {
      float* zwp = ws + OFF_ZW + (size_t)b * Mn + m0;
      zwp[0] = zw.x; zwp[1] = zw.y; zwp[2] = zw.z; zwp[3] = zw.w;
    }
  } else {
    // ===== P2: t2 = v.phi -> softmax_d -> P2 ; also vsum
    int bl2 = bl - 400;
    int b = bl2 >> 6, cgrp = bl2 & 63, c0 = cgrp * 8;
    const float* v = ws + OFF_V + ((size_t)b * Cn + c0) * Sn;
    #pragma unroll
    for (int cc = 0; cc < 8; ++cc) sh.p.vl[cc][t] = v[(size_t)cc * Sn + t];
    __syncthreads();
    int k = t >> 7, d = t & 127;
    int dd = d < Ln ? d : Ln - 1;
    const float* pp = phi + (size_t)k * Sn * Ln + dd;
    float acc[8] = {0, 0, 0, 0, 0, 0, 0, 0};
    for (int s = 0; s < Sn; s += 4) {
      float p0 = pp[(size_t)(s + 0) * Ln];
      float p1 = pp[(size_t)(s + 1) * Ln];
      float p2 = pp[(size_t)(s + 2) * Ln];
      float p3 = pp[(size_t)(s + 3) * Ln];
      #pragma unroll
      for (int cc = 0; cc < 8; ++cc) {
        float4 vv = *(const float4*)&sh.p.vl[cc][s];
        acc[cc] += vv.x * p0 + vv.y * p1 + vv.z * p2 + vv.w * p3;
      }
    }
    if (d < Ln) {
      #pragma unroll
      for (int cc = 0; cc < 8; ++cc) sh.p.t2l[k * 8 + cc][d] = acc[cc];
    }
    __syncthreads();
    // 16 groups of 16 lanes; group gg = k2*8+cc2 reduces over d (100 entries)
    int gg = t >> 4, l = t & 15;
    int k2 = gg >> 3, cc2 = gg & 7;
    float mx = -1e30f;
    for (int dq = l; dq < Ln; dq += 16) mx = fmaxf(mx, sh.p.t2l[gg][dq]);
    #pragma unroll
    for (int o = 8; o; o >>= 1) mx = fmaxf(mx, __shfl_xor(mx, o));
    float se = 0.f;
    for (int dq = l; dq < Ln; dq += 16) se += expf(sh.p.t2l[gg][dq] - mx);
    #pragma unroll
    for (int o = 8; o; o >>= 1) se += __shfl_xor(se, o);
    float* p2row = ws + OFF_P2 + ((size_t)b * Cn + c0 + cc2) * Mn + k2 * Ln;
    for (int dq = l; dq < Ln; dq += 16)
      p2row[dq] = expf(sh.p.t2l[gg][dq] - mx) / se;
    if (k2 == 0) {                            // vsum[c] = sum_s v[c,s]
      float vs = 0.f;
      for (int i2 = 0; i2 < 16; ++i2) vs += sh.p.vl[cc2][i2 * 16 + l];
      #pragma unroll
      for (int o = 8; o; o >>= 1) vs += __shfl_xor(vs, o);
      if (l == 0) ws[OFF_VSUM + (size_t)b * Cn + c0 + cc2] = vs;
    }
  }
}

// ---------- D3: per-batch Gram softmax (no max needed: |zn.zn|<=1) -> zp_w
//              -> attn = sigmoid((vsum + P2.zp_w)/256) ----------
__global__ void __launch_bounds__(1024) k_fin(float* __restrict__ ws,
                                              float* __restrict__ out) {
  int b = blockIdx.x, t = threadIdx.x;
  __shared__ float zwl[200], zpl[200];
  __shared__ __align__(16) float zl[8][256];
  __shared__ float redA[4][4][4];
  const float* zn  = ws + OFF_ZN  + (size_t)b * Mn * Sn;
  const float* znT = ws + OFF_ZNT + (size_t)b * Sn * Mn;
  if (t < Mn) zwl[t] = ws[OFF_ZW + (size_t)b * Mn + t];
  int g = t >> 8, n = t & 255, w = (t >> 6) & 3;
  for (int mc = 0; mc < 25; ++mc) {
    int m1 = mc * 4 + g, m2 = m1 + 100;      // covers [0,100) and [100,200)
    __syncthreads();                          // protects zl reuse (+ zwl 1st iter)
    zl[g][n]     = zn[(size_t)m1 * Sn + n];
    zl[g + 4][n] = zn[(size_t)m2 * Sn + n];
    __syncthreads();
    float d1 = 0.f, d2 = 0.f;
    if (n < Mn) {
      const float* zc = znT + n;              // column n, coalesced across lanes
      for (int s = 0; s < Sn; s += 4) {
        float4 za = *(const float4*)&zl[g][s];
        float4 zb = *(const float4*)&zl[g + 4][s];
        float c0v = zc[(size_t)(s + 0) * Mn], c1v = zc[(size_t)(s + 1) * Mn];
        float c2v = zc[(size_t)(s + 2) * Mn], c3v = zc[(size_t)(s + 3) * Mn];
        d1 += za.x * c0v + za.y * c1v + za.z * c2v + za.w * c3v;
        d2 += zb.x * c0v + zb.y * c1v + zb.z * c2v + zb.w * c3v;
      }
    }
    float e1 = (n < Mn) ? expf(d1) : 0.f;     // d in [-1,1] -> stable
    float e2 = (n < Mn) ? expf(d2) : 0.f;
    float zwn = (n < Mn) ? zwl[n] : 0.f;
    float ez1 = e1 * zwn, ez2 = e2 * zwn;
    #pragma unroll
    for (int o = 32; o; o >>= 1) {
      e1 += __shfl_xor(e1, o); ez1 += __shfl_xor(ez1, o);
      e2 += __shfl_xor(e2, o); ez2 += __shfl_xor(ez2, o);
    }
    if ((t & 63) == 0) {
      redA[g][w][0] = e1; redA[g][w][1] = ez1;
      redA[g][w][2] = e2; redA[g][w][3] = ez2;
    }
    __syncthreads();
    if (n == 0) {
      float s1 = redA[g][0][0] + redA[g][1][0] + redA[g][2][0] + redA[g][3][0];
      float z1 = redA[g][0][1] + redA[g][1][1] + redA[g][2][1] + redA[g][3][1];
      float s2 = redA[g][0][2] + redA[g][1][2] + redA[g][2][2] + redA[g][3][2];
      float z2 = redA[g][0][3] + redA[g][1][3] + redA[g][2][3] + redA[g][3][3];
      zpl[m1] = z1 / s1;
      zpl[m2] = z2 / s2;
    }
  }
  __syncthreads();
  // final dot: thread pair (c = t>>1, half = t&1) each does 100 of the 200
  int c = t >> 1, half = t & 1;
  const float* p2 = ws + OFF_P2 + ((size_t)b * Cn + c) * Mn + half * Ln;
  float acc = 0.f;
  for (int j = 0; j < Ln; j += 4) {
    float4 pv = *(const float4*)(p2 + j);
    acc += pv.x * zpl[half * Ln + j]     + pv.y * zpl[half * Ln + j + 1]
         + pv.z * zpl[half * Ln + j + 2] + pv.w * zpl[half * Ln + j + 3];
  }
  float tot = acc + __shfl_xor(acc, 1);
  if (half == 0) {
    float f = (ws[OFF_VSUM + (size_t)b * Cn + c] + tot) * (1.0f / 256.0f);
    out[(size_t)b * Cn + c] = 1.0f / (1.0f + expf(-f));
  }
}

extern "C" void kernel_launch(void* const* d_in, const int* in_sizes, int n_in,
                              void* d_out, int out_size, void* d_ws, size_t ws_size,
                              hipStream_t stream) {
  const float* x   = (const float*)d_in[0];
  const float* psi = (const float*)d_in[1];
  const float* phi = (const float*)d_in[2];
  const float* ow  = (const float*)d_in[3];
  float* out = (float*)d_out;
  float* ws  = (float*)d_ws;

  hipLaunchKernelGGL(k_pool, dim3(4097), dim3(256), 0, stream, x, ow, ws);
  hipLaunchKernelGGL(k_mid,  dim3(912),  dim3(256), 0, stream, psi, phi, ws);
  hipLaunchKernelGGL(k_fin,  dim3(8),    dim3(1024), 0, stream, ws, out);
}

// Round 8
// 136.620 us; speedup vs baseline: 2.7661x; 2.7661x over previous
//
#include <hip/hip_runtime.h>
#include <math.h>

constexpr int Bn = 8, Cn = 512, Sn = 256, Mn = 200, Ln = 100;

// workspace layout (floats) — ~10.8 MB
constexpr size_t OFF_V    = 0;                                 // [B][C][S]
constexpr size_t OFF_ZN   = OFF_V    + (size_t)Bn*Cn*Sn;       // [B][M][S] normalized z
constexpr size_t OFF_ZNT  = OFF_ZN   + (size_t)Bn*Mn*Sn;       // [B][S][M] zn transposed
constexpr size_t OFF_P2   = OFF_ZNT  + (size_t)Bn*Sn*Mn;       // [B][C][M] softmax_d(v.phi)
constexpr size_t OFF_ZW   = OFF_P2   + (size_t)Bn*Cn*Mn;       // [B][M]  z.wsum
constexpr size_t OFF_ZPW  = OFF_ZW   + (size_t)Bn*Mn;          // [B][M]  propagated.wsum
constexpr size_t OFF_VSUM = OFF_ZPW  + (size_t)Bn*Mn;          // [B][C]  sum_s v
constexpr size_t OFF_WSUM = OFF_VSUM + (size_t)Bn*Cn;          // [S]     row-sums of out_w

// ---------- vectorized block reductions (4 waves / 256 threads) ----------
__device__ __forceinline__ float4 blk_max_f4(float4 x, float4* red) {
  #pragma unroll
  for (int o = 32; o; o >>= 1) {
    x.x = fmaxf(x.x, __shfl_xor(x.x, o));
    x.y = fmaxf(x.y, __shfl_xor(x.y, o));
    x.z = fmaxf(x.z, __shfl_xor(x.z, o));
    x.w = fmaxf(x.w, __shfl_xor(x.w, o));
  }
  __syncthreads();
  if ((threadIdx.x & 63) == 0) red[threadIdx.x >> 6] = x;
  __syncthreads();
  float4 r = red[0];
  #pragma unroll
  for (int w = 1; w < 4; ++w) {
    r.x = fmaxf(r.x, red[w].x); r.y = fmaxf(r.y, red[w].y);
    r.z = fmaxf(r.z, red[w].z); r.w = fmaxf(r.w, red[w].w);
  }
  return r;
}
__device__ __forceinline__ float4 blk_sum_f4(float4 x, float4* red) {
  #pragma unroll
  for (int o = 32; o; o >>= 1) {
    x.x += __shfl_xor(x.x, o); x.y += __shfl_xor(x.y, o);
    x.z += __shfl_xor(x.z, o); x.w += __shfl_xor(x.w, o);
  }
  __syncthreads();
  if ((threadIdx.x & 63) == 0) red[threadIdx.x >> 6] = x;
  __syncthreads();
  float4 r = red[0];
  #pragma unroll
  for (int w = 1; w < 4; ++w) {
    r.x += red[w].x; r.y += red[w].y; r.z += red[w].z; r.w += red[w].w;
  }
  return r;
}

// ---------- D1: R2-proven pool: 8x8 block-mean, 1 plane/block + wsum ----------
__global__ void __launch_bounds__(256) k_pool(const float* __restrict__ x,
                                              const float* __restrict__ ow,
                                              float* __restrict__ ws) {
  int t = threadIdx.x;
  if (blockIdx.x == 4096) {                  // wsum[s] = sum_t out_w[s,t]
    const float* row = ow + (size_t)t * Sn;
    float s = 0.f;
    for (int j = 0; j < Sn; j += 4) {
      float4 f = *(const float4*)(row + j);
      s += f.x + f.y + f.z + f.w;
    }
    ws[OFF_WSUM + t] = s;
    return;
  }
  int bc = blockIdx.x;                       // (b,c) plane, 0..4095
  const float* plane = x + (size_t)bc * 16384;
  float part[16];
  #pragma unroll
  for (int i = 0; i < 16; ++i) {
    float4 f = *(const float4*)(plane + i * 1024 + t * 4);
    part[i] = f.x + f.y + f.z + f.w;
  }
  __shared__ float lds[256][17];
  #pragma unroll
  for (int i = 0; i < 16; ++i) lds[t][i] = part[i];
  __syncthreads();
  int i = t >> 4, jj = t & 15;
  float s = 0.f;
  #pragma unroll
  for (int r = 0; r < 8; ++r)
    s += lds[32 * r + 2 * jj][i] + lds[32 * r + 2 * jj + 1][i];
  ws[OFF_V + (size_t)bc * 256 + t] = s * (1.0f / 64.0f);
}

// ---------- D2: blocks 0..399 = psz ; blocks 400..911 = P2 + vsum ----------
struct PszS { float pc[4][256]; float As[4][512]; };
struct P2S  { float vl[8][256]; float t2l[16][104]; };
union MidS { PszS z; P2S p; };

__global__ void __launch_bounds__(256) k_mid(const float* __restrict__ psi,
                                             const float* __restrict__ phi,
                                             float* __restrict__ ws) {
  __shared__ MidS sh;
  __shared__ float4 red4[4];
  int bl = blockIdx.x, t = threadIdx.x;

  if (bl < 400) {
    // ===== psz: t1 = v.psi -> softmax_c -> A(LDS) -> z -> zn/znT/zw
    int b = bl / 50, g = bl % 50, m0 = g * 4;
    const float* v = ws + OFF_V + (size_t)b * Cn * Sn;
    for (int e = t; e < 4 * 256; e += 256) {
      int mm = e >> 8, s = e & 255;
      int m = m0 + mm, k = m / Ln, d = m % Ln;
      sh.z.pc[mm][s] = psi[(size_t)k * Sn * Ln + (size_t)s * Ln + d];
    }
    __syncthreads();
    float acc[2][4];
    #pragma unroll
    for (int mm = 0; mm < 4; ++mm) { acc[0][mm] = 0.f; acc[1][mm] = 0.f; }
    const float* vp0 = v + (size_t)t * Sn;
    const float* vp1 = v + (size_t)(t + 256) * Sn;
    for (int s = 0; s < Sn; s += 4) {
      float4 v0 = *(const float4*)(vp0 + s);
      float4 v1 = *(const float4*)(vp1 + s);
      #pragma unroll
      for (int mm = 0; mm < 4; ++mm) {
        float4 p = *(const float4*)&sh.z.pc[mm][s];
        acc[0][mm] += v0.x * p.x + v0.y * p.y + v0.z * p.z + v0.w * p.w;
        acc[1][mm] += v1.x * p.x + v1.y * p.y + v1.z * p.z + v1.w * p.w;
      }
    }
    float4 a = make_float4(fmaxf(acc[0][0], acc[1][0]), fmaxf(acc[0][1], acc[1][1]),
                           fmaxf(acc[0][2], acc[1][2]), fmaxf(acc[0][3], acc[1][3]));
    float4 mx = blk_max_f4(a, red4);
    float e00 = expf(acc[0][0] - mx.x), e10 = expf(acc[1][0] - mx.x);
    float e01 = expf(acc[0][1] - mx.y), e11 = expf(acc[1][1] - mx.y);
    float e02 = expf(acc[0][2] - mx.z), e12 = expf(acc[1][2] - mx.z);
    float e03 = expf(acc[0][3] - mx.w), e13 = expf(acc[1][3] - mx.w);
    float4 se = blk_sum_f4(make_float4(e00 + e10, e01 + e11, e02 + e12, e03 + e13),
                           red4);
    sh.z.As[0][t] = e00 / se.x; sh.z.As[0][t + 256] = e10 / se.x;
    sh.z.As[1][t] = e01 / se.y; sh.z.As[1][t + 256] = e11 / se.y;
    sh.z.As[2][t] = e02 / se.z; sh.z.As[2][t + 256] = e12 / se.z;
    sh.z.As[3][t] = e03 / se.w; sh.z.As[3][t + 256] = e13 / se.w;
    __syncthreads();
    float zv[4] = {0, 0, 0, 0};
    for (int c = 0; c < Cn; c += 4) {
      float w0 = v[(size_t)(c + 0) * Sn + t];
      float w1 = v[(size_t)(c + 1) * Sn + t];
      float w2 = v[(size_t)(c + 2) * Sn + t];
      float w3 = v[(size_t)(c + 3) * Sn + t];
      #pragma unroll
      for (int mm = 0; mm < 4; ++mm) {
        float4 aa = *(const float4*)&sh.z.As[mm][c];
        zv[mm] += aa.x * w0 + aa.y * w1 + aa.z * w2 + aa.w * w3;
      }
    }
    float wsv = ws[OFF_WSUM + t];
    float4 n2 = blk_sum_f4(make_float4(zv[0]*zv[0], zv[1]*zv[1],
                                       zv[2]*zv[2], zv[3]*zv[3]), red4);
    float4 zw = blk_sum_f4(make_float4(zv[0]*wsv, zv[1]*wsv,
                                       zv[2]*wsv, zv[3]*wsv), red4);
    float zn0 = zv[0] * (1.0f / (sqrtf(n2.x) + 1e-6f));
    float zn1 = zv[1] * (1.0f / (sqrtf(n2.y) + 1e-6f));
    float zn2 = zv[2] * (1.0f / (sqrtf(n2.z) + 1e-6f));
    float zn3 = zv[3] * (1.0f / (sqrtf(n2.w) + 1e-6f));
    float* zo = ws + OFF_ZN + ((size_t)b * Mn + m0) * Sn;
    zo[0 * Sn + t] = zn0; zo[1 * Sn + t] = zn1;
    zo[2 * Sn + t] = zn2; zo[3 * Sn + t] = zn3;
    *(float4*)&ws[OFF_ZNT + ((size_t)b * Sn + t) * Mn + m0] =
        make_float4(zn0, zn1, zn2, zn3);
    if (t == 0) {
      float* zwp = ws + OFF_ZW + (size_t)b * Mn + m0;
      zwp[0] = zw.x; zwp[1] = zw.y; zwp[2] = zw.z; zwp[3] = zw.w;
    }
  } else {
    // ===== P2: t2 = v.phi -> softmax_d -> P2 ; also vsum
    int bl2 = bl - 400;
    int b = bl2 >> 6, cgrp = bl2 & 63, c0 = cgrp * 8;
    const float* v = ws + OFF_V + ((size_t)b * Cn + c0) * Sn;
    #pragma unroll
    for (int cc = 0; cc < 8; ++cc) sh.p.vl[cc][t] = v[(size_t)cc * Sn + t];
    __syncthreads();
    int k = t >> 7, d = t & 127;
    int dd = d < Ln ? d : Ln - 1;
    const float* pp = phi + (size_t)k * Sn * Ln + dd;
    float acc[8] = {0, 0, 0, 0, 0, 0, 0, 0};
    for (int s = 0; s < Sn; s += 4) {
      float p0 = pp[(size_t)(s + 0) * Ln];
      float p1 = pp[(size_t)(s + 1) * Ln];
      float p2 = pp[(size_t)(s + 2) * Ln];
      float p3 = pp[(size_t)(s + 3) * Ln];
      #pragma unroll
      for (int cc = 0; cc < 8; ++cc) {
        float4 vv = *(const float4*)&sh.p.vl[cc][s];
        acc[cc] += vv.x * p0 + vv.y * p1 + vv.z * p2 + vv.w * p3;
      }
    }
    if (d < Ln) {
      #pragma unroll
      for (int cc = 0; cc < 8; ++cc) sh.p.t2l[k * 8 + cc][d] = acc[cc];
    }
    __syncthreads();
    int gg = t >> 4, l = t & 15;
    int k2 = gg >> 3, cc2 = gg & 7;
    float mx = -1e30f;
    for (int dq = l; dq < Ln; dq += 16) mx = fmaxf(mx, sh.p.t2l[gg][dq]);
    #pragma unroll
    for (int o = 8; o; o >>= 1) mx = fmaxf(mx, __shfl_xor(mx, o));
    float se = 0.f;
    for (int dq = l; dq < Ln; dq += 16) se += expf(sh.p.t2l[gg][dq] - mx);
    #pragma unroll
    for (int o = 8; o; o >>= 1) se += __shfl_xor(se, o);
    float* p2row = ws + OFF_P2 + ((size_t)b * Cn + c0 + cc2) * Mn + k2 * Ln;
    for (int dq = l; dq < Ln; dq += 16)
      p2row[dq] = expf(sh.p.t2l[gg][dq] - mx) / se;
    if (k2 == 0) {
      float vs = 0.f;
      for (int i2 = 0; i2 < 16; ++i2) vs += sh.p.vl[cc2][i2 * 16 + l];
      #pragma unroll
      for (int o = 8; o; o >>= 1) vs += __shfl_xor(vs, o);
      if (l == 0) ws[OFF_VSUM + (size_t)b * Cn + c0 + cc2] = vs;
    }
  }
}

// ---------- D3: Gram softmax rows -> zp_w ; 400 blocks (b, 4 m-rows) ----------
__global__ void __launch_bounds__(256) k_gram(float* __restrict__ ws) {
  int bl = blockIdx.x, t = threadIdx.x;
  int b = bl / 50, g = bl % 50, m0 = g * 4;
  __shared__ __align__(16) float zl[4][256];
  __shared__ float zwl[200];
  __shared__ float4 red4[4];
  const float* zn  = ws + OFF_ZN  + (size_t)b * Mn * Sn;
  const float* znT = ws + OFF_ZNT + (size_t)b * Sn * Mn;
  #pragma unroll
  for (int mm = 0; mm < 4; ++mm)
    zl[mm][t] = zn[(size_t)(m0 + mm) * Sn + t];
  if (t < Mn) zwl[t] = ws[OFF_ZW + (size_t)b * Mn + t];
  __syncthreads();
  bool act = t < Mn;
  float dot[4] = {0, 0, 0, 0};
  if (act) {
    const float* zc = znT + t;               // column n = t, coalesced across lanes
    for (int s = 0; s < Sn; s += 4) {
      float c0v = zc[(size_t)(s + 0) * Mn], c1v = zc[(size_t)(s + 1) * Mn];
      float c2v = zc[(size_t)(s + 2) * Mn], c3v = zc[(size_t)(s + 3) * Mn];
      #pragma unroll
      for (int mm = 0; mm < 4; ++mm) {
        float4 za = *(const float4*)&zl[mm][s];
        dot[mm] += za.x * c0v + za.y * c1v + za.z * c2v + za.w * c3v;
      }
    }
  }
  // |dot| <= 1 (normalized rows) -> exp is stable without max-subtract
  float4 e;
  e.x = act ? expf(dot[0]) : 0.f;
  e.y = act ? expf(dot[1]) : 0.f;
  e.z = act ? expf(dot[2]) : 0.f;
  e.w = act ? expf(dot[3]) : 0.f;
  float4 se = blk_sum_f4(e, red4);
  float zwn = act ? zwl[t] : 0.f;
  float4 sez = blk_sum_f4(make_float4(e.x*zwn, e.y*zwn, e.z*zwn, e.w*zwn), red4);
  if (t == 0) {
    float* zp = ws + OFF_ZPW + (size_t)b * Mn + m0;
    zp[0] = sez.x / se.x; zp[1] = sez.y / se.y;
    zp[2] = sez.z / se.z; zp[3] = sez.w / se.w;
  }
}

// ---------- D4: out[b,c] = sigmoid((vsum + P2[c,:].zp_w)/256) ; 512 blocks ----------
__global__ void __launch_bounds__(256) k_dot(float* __restrict__ ws,
                                             float* __restrict__ out) {
  int bl = blockIdx.x, t = threadIdx.x;
  int b = bl >> 6, cg = bl & 63, c0 = cg * 8;
  __shared__ float zpl[200];
  if (t < Mn) zpl[t] = ws[OFF_ZPW + (size_t)b * Mn + t];
  __syncthreads();
  int c = c0 + (t >> 5), l = t & 31;
  const float* p2 = ws + OFF_P2 + ((size_t)b * Cn + c) * Mn;
  float acc = 0.f;
  for (int m = l; m < Mn; m += 32) acc += p2[m] * zpl[m];   // 128B coalesced
  #pragma unroll
  for (int o = 16; o; o >>= 1) acc += __shfl_xor(acc, o);
  if (l == 0) {
    float f = (ws[OFF_VSUM + (size_t)b * Cn + c] + acc) * (1.0f / 256.0f);
    out[(size_t)b * Cn + c] = 1.0f / (1.0f + expf(-f));
  }
}

extern "C" void kernel_launch(void* const* d_in, const int* in_sizes, int n_in,
                              void* d_out, int out_size, void* d_ws, size_t ws_size,
                              hipStream_t stream) {
  const float* x   = (const float*)d_in[0];
  const float* psi = (const float*)d_in[1];
  const float* phi = (const float*)d_in[2];
  const float* ow  = (const float*)d_in[3];
  float* out = (float*)d_out;
  float* ws  = (float*)d_ws;

  hipLaunchKernelGGL(k_pool, dim3(4097), dim3(256), 0, stream, x, ow, ws);
  hipLaunchKernelGGL(k_mid,  dim3(912),  dim3(256), 0, stream, psi, phi, ws);
  hipLaunchKernelGGL(k_gram, dim3(400),  dim3(256), 0, stream, ws);
  hipLaunchKernelGGL(k_dot,  dim3(512),  dim3(256), 0, stream, ws, out);
}